// Round 1
// baseline (99.086 us; speedup 1.0000x reference)
//
#include <hip/hip_runtime.h>

// Batched scalar neural-ODE, RK4, 99 steps, tiny 2->4->1 LeakyReLU MLP.
// One thread per batch element. All weights uniform (scalar-loaded).
// LeakyReLU folded into the output dot product:
//   leaky(h) = 0.505*h + 0.495*|h|   (slope 0.01)
//   w*leaky(h) = (0.505w)*h + (0.495w)*|h|   -> |h| is a free VOP3 abs modifier.

#define NSTEP 100

__global__ __launch_bounds__(256, 2) void rk4_net_kernel(
    const float* __restrict__ x, const float* __restrict__ u,
    const float* __restrict__ W1, const float* __restrict__ b1,
    const float* __restrict__ W2, const float* __restrict__ b2,
    float* __restrict__ out, int B)
{
    const int b = blockIdx.x * blockDim.x + threadIdx.x;
    if (b >= B) return;

    // Uniform weights (W1 row-major (2,4): row 0 multiplies s, row 1 multiplies u)
    const float A0 = W1[0], A1 = W1[1], A2 = W1[2], A3 = W1[3];
    const float U0 = W1[4], U1 = W1[5], U2 = W1[6], U3 = W1[7];
    const float w0 = W2[0], w1 = W2[1], w2 = W2[2], w3 = W2[3];
    const float bias2 = b2[0];

    const float uu = u[b];
    float s = x[b];

    // Per-thread hidden-layer constants: C_i = u*W1[1][i] + b1[i]
    const float C0 = fmaf(uu, U0, b1[0]);
    const float C1 = fmaf(uu, U1, b1[1]);
    const float C2 = fmaf(uu, U2, b1[2]);
    const float C3 = fmaf(uu, U3, b1[3]);

    // LeakyReLU folded weights
    const float al = 0.505f, be = 0.495f;
    const float wa0 = al * w0, wa1 = al * w1, wa2 = al * w2, wa3 = al * w3;
    const float wb0 = be * w0, wb1 = be * w1, wb2 = be * w2, wb3 = be * w3;

    auto dyn = [&](float sv) -> float {
        float h0 = fmaf(sv, A0, C0);
        float h1 = fmaf(sv, A1, C1);
        float h2 = fmaf(sv, A2, C2);
        float h3 = fmaf(sv, A3, C3);
        // two independent FMA chains (depth 4) -> good ILP, |h| via abs modifier
        float p = fmaf(h0, wa0, bias2);
        float q = __builtin_fabsf(h0) * wb0;
        p = fmaf(h1, wa1, p);
        q = fmaf(__builtin_fabsf(h1), wb1, q);
        p = fmaf(h2, wa2, p);
        q = fmaf(__builtin_fabsf(h2), wb2, q);
        p = fmaf(h3, wa3, p);
        q = fmaf(__builtin_fabsf(h3), wb3, q);
        return p + q;
    };

    auto step = [&](float sv) -> float {
        float k1 = dyn(sv);
        float k2 = dyn(fmaf(0.5f, k1, sv));
        float k3 = dyn(fmaf(0.5f, k2, sv));
        float k4 = dyn(sv + k3);
        float sum = fmaf(2.0f, k2, k1);
        sum = fmaf(2.0f, k3, sum);
        sum += k4;
        return fmaf(0.16666667f, sum, sv);  // DT/6
    };

    // Output: out[b*100 + t]; buffer 4 steps, store float4 (base is 16B aligned).
    float4* o4 = (float4*)(out + (size_t)b * NSTEP);

    float4 v;
    v.x = s;                 // t = 0 is the initial state
    s = step(s); v.y = s;
    s = step(s); v.z = s;
    s = step(s); v.w = s;
    o4[0] = v;

#pragma unroll 1
    for (int c = 1; c < 25; ++c) {
        s = step(s); v.x = s;
        s = step(s); v.y = s;
        s = step(s); v.z = s;
        s = step(s); v.w = s;
        o4[c] = v;
    }
}

extern "C" void kernel_launch(void* const* d_in, const int* in_sizes, int n_in,
                              void* d_out, int out_size, void* d_ws, size_t ws_size,
                              hipStream_t stream) {
    const float* x  = (const float*)d_in[0];
    const float* u  = (const float*)d_in[1];
    const float* W1 = (const float*)d_in[2];
    const float* b1 = (const float*)d_in[3];
    const float* W2 = (const float*)d_in[4];
    const float* b2 = (const float*)d_in[5];
    float* out = (float*)d_out;

    const int B = in_sizes[0];
    const int block = 256;
    const int grid = (B + block - 1) / block;
    hipLaunchKernelGGL(rk4_net_kernel, dim3(grid), dim3(block), 0, stream,
                       x, u, W1, b1, W2, b2, out, B);
}